// Round 1
// baseline (587.773 us; speedup 1.0000x reference)
//
#include <hip/hip_runtime.h>
#include <stdint.h>

#define B 8
#define N 460800
#define PRE 2000
#define POST 1000
#define CAP 8192
#define NBIN 4096
#define RANKP 2048
#define NWORD 32
#define CHUNK 4096
#define NMS_T 0.7f
#define XCLIP 4.135166556742356

__device__ __forceinline__ uint32_t fkey(float f) {
    uint32_t u = __float_as_uint(f);
    return (u & 0x80000000u) ? ~u : (u | 0x80000000u);
}

// ---------------- Stage 1: per-image histogram of score keys (top 12 bits) ----------------
__global__ void k_hist(const float* __restrict__ obj, uint32_t* __restrict__ hist) {
    __shared__ uint32_t lh[NBIN];
    int b = blockIdx.y;
    for (int i = threadIdx.x; i < NBIN; i += blockDim.x) lh[i] = 0;
    __syncthreads();
    const float* s = obj + (size_t)b * N;
    int start = blockIdx.x * CHUNK;
    int end = start + CHUNK; if (end > N) end = N;
    for (int i = start + threadIdx.x; i < end; i += blockDim.x) {
        uint32_t k = fkey(s[i]);
        atomicAdd(&lh[k >> 20], 1u);
    }
    __syncthreads();
    uint32_t* gh = hist + (size_t)b * NBIN;
    for (int i = threadIdx.x; i < NBIN; i += blockDim.x) {
        uint32_t v = lh[i];
        if (v) atomicAdd(&gh[i], v);
    }
}

// ---------------- Stage 2: find cutoff bin (2000th largest falls in it) ----------------
__global__ void k_cut(const uint32_t* __restrict__ hist, uint32_t* __restrict__ cut) {
    int b = blockIdx.x;
    int lane = threadIdx.x;  // 0..63, one wave
    const uint32_t* h = hist + (size_t)b * NBIN;
    uint32_t gs = 0;
    for (int t = 0; t < 64; ++t) gs += h[lane * 64 + t];
    // suffix sum over groups (group g = bins [g*64, g*64+64))
    uint32_t suf = gs;
    for (int d = 1; d < 64; d <<= 1) {
        uint32_t v = __shfl_down(suf, d);
        if (lane + d < 64) suf += v;
    }
    unsigned long long m = __ballot(suf >= PRE);
    int G = 63 - __clzll(m);            // highest group with suffix >= PRE
    uint32_t A = 0;
    if (G < 63) A = __shfl(suf, G + 1); // count strictly above group G
    uint32_t hv = h[G * 64 + lane];
    uint32_t suf2 = hv;
    for (int d = 1; d < 64; d <<= 1) {
        uint32_t v = __shfl_down(suf2, d);
        if (lane + d < 64) suf2 += v;
    }
    unsigned long long m2 = __ballot(A + suf2 >= PRE);
    int t2 = 63 - __clzll(m2);
    if (lane == 0) cut[b] = (uint32_t)(G * 64 + t2);
}

// ---------------- Stage 3: compact candidates (bin >= cut) ----------------
__global__ void k_compact(const float* __restrict__ obj, const uint32_t* __restrict__ cut,
                          uint32_t* __restrict__ cnt, unsigned long long* __restrict__ cand) {
    int b = blockIdx.y;
    uint32_t cb = cut[b];
    const float* s = obj + (size_t)b * N;
    int start = blockIdx.x * CHUNK;
    int end = start + CHUNK; if (end > N) end = N;
    for (int i = start + threadIdx.x; i < end; i += blockDim.x) {
        uint32_t k = fkey(s[i]);
        if ((k >> 20) >= cb) {
            uint32_t pos = atomicAdd(&cnt[b], 1u);
            if (pos < CAP)
                cand[(size_t)b * CAP + pos] =
                    ((unsigned long long)k << 32) | (uint32_t)(~(uint32_t)i);
        }
    }
}

// ---------------- Stage 4: bitonic sort candidates desc by (key, ~idx) ----------------
__global__ __launch_bounds__(1024) void k_sort(const uint32_t* __restrict__ cnt,
                                               const unsigned long long* __restrict__ cand,
                                               uint32_t* __restrict__ topidx) {
    __shared__ unsigned long long sm[CAP];  // 64 KiB
    int b = blockIdx.x;
    uint32_t n = cnt[b]; if (n > CAP) n = CAP;
    const unsigned long long* c = cand + (size_t)b * CAP;
    for (int t = threadIdx.x; t < CAP; t += 1024) sm[t] = (t < (int)n) ? c[t] : 0ull;
    __syncthreads();
    for (unsigned k = 2; k <= CAP; k <<= 1) {
        for (unsigned j = k >> 1; j > 0; j >>= 1) {
            for (unsigned t = threadIdx.x; t < CAP; t += 1024) {
                unsigned x = t ^ j;
                if (x > t) {
                    unsigned long long a = sm[t], bb = sm[x];
                    bool desc = ((t & k) == 0);
                    if (desc ? (a < bb) : (a > bb)) { sm[t] = bb; sm[x] = a; }
                }
            }
            __syncthreads();
        }
    }
    for (int r = threadIdx.x; r < PRE; r += 1024)
        topidx[(size_t)b * RANKP + r] = ~(uint32_t)sm[r];
}

// ---------------- Stage 5: decode + clip + small-box mask for top-2000 ----------------
__global__ void k_decode(const float4* __restrict__ anchors, const float4* __restrict__ deltas,
                         const uint32_t* __restrict__ topidx, float4* __restrict__ boxes,
                         unsigned long long* __restrict__ valid) {
    int b = blockIdx.y;
    int r = blockIdx.x * blockDim.x + threadIdx.x;  // 0..2047
    float4 out = make_float4(0.f, 0.f, 0.f, 0.f);
    bool ok = false;
    if (r < PRE) {
        uint32_t i = topidx[(size_t)b * RANKP + r];
        if (i < N) {
            float4 a = anchors[i];
            float4 d = deltas[(size_t)b * N + i];
            float w = a.z - a.x, h = a.w - a.y;
            float cx = a.x + 0.5f * w, cy = a.y + 0.5f * h;
            float dw = fminf(d.z, (float)XCLIP);
            float dh = fminf(d.w, (float)XCLIP);
            float pcx = d.x * w + cx, pcy = d.y * h + cy;
            float pw = expf(dw) * w, ph = expf(dh) * h;
            float x1 = pcx - 0.5f * pw, y1 = pcy - 0.5f * ph;
            float x2 = pcx + 0.5f * pw, y2 = pcy + 0.5f * ph;
            x1 = fminf(fmaxf(x1, 0.f), 1024.f);
            y1 = fminf(fmaxf(y1, 0.f), 1024.f);
            x2 = fminf(fmaxf(x2, 0.f), 1024.f);
            y2 = fminf(fmaxf(y2, 0.f), 1024.f);
            out = make_float4(x1, y1, x2, y2);
            ok = !((x2 - x1 < 1e-3f) || (y2 - y1 < 1e-3f));
        }
    }
    boxes[(size_t)b * RANKP + r] = out;
    unsigned long long bal = __ballot(ok);
    if ((threadIdx.x & 63) == 0) valid[(size_t)b * NWORD + (r >> 6)] = bal;
}

// ---------------- Stage 6a: pairwise suppression bitmask ----------------
__global__ void k_mask(const float4* __restrict__ boxes, unsigned long long* __restrict__ sup) {
    int b = blockIdx.z, ti = blockIdx.y, tj = blockIdx.x;
    if (tj < ti) return;  // lower-triangle words never read
    __shared__ float4 jb[64];
    __shared__ float ja[64];
    int t = threadIdx.x;  // 64 threads
    const float4* bx = boxes + (size_t)b * RANKP;
    float4 v = bx[tj * 64 + t];
    jb[t] = v;
    ja[t] = (v.z - v.x) * (v.w - v.y);
    int i = ti * 64 + t;
    float4 bi = bx[i];
    float ai = (bi.z - bi.x) * (bi.w - bi.y);
    __syncthreads();
    unsigned long long word = 0;
    for (int jj = 0; jj < 64; ++jj) {
        int j = tj * 64 + jj;
        float4 bj = jb[jj];
        float xx1 = fmaxf(bi.x, bj.x), yy1 = fmaxf(bi.y, bj.y);
        float xx2 = fminf(bi.z, bj.z), yy2 = fminf(bi.w, bj.w);
        float iw = fmaxf(xx2 - xx1, 0.f), ih = fmaxf(yy2 - yy1, 0.f);
        float inter = iw * ih;
        float iou = inter / (ai + ja[jj] - inter);  // NaN/inf compare-false matches jnp
        if (j > i && iou > NMS_T) word |= 1ull << jj;
    }
    sup[((size_t)b * RANKP + i) * NWORD + tj] = word;
}

// ---------------- Stage 6b: sequential greedy collect (1 wave / image) ----------------
__global__ void k_collect(const unsigned long long* __restrict__ valid,
                          const unsigned long long* __restrict__ sup,
                          unsigned long long* __restrict__ keep) {
    int b = blockIdx.x;
    int lane = threadIdx.x;  // 64
    int w = lane & 31;
    unsigned long long remv = (lane < 32) ? ~valid[(size_t)b * NWORD + lane] : 0ull;
    const unsigned long long* S = sup + (size_t)b * RANKP * NWORD;
    unsigned long long nxt = S[w];  // prefetch row 0
    for (int i = 0; i < PRE; ++i) {
        unsigned long long cur = nxt;
        nxt = S[(size_t)(i + 1) * NWORD + w];  // row PRE exists (RANKP padding)
        int wi = i >> 6;
        unsigned long long rw = __shfl(remv, wi);
        bool removed = (rw >> (i & 63)) & 1;
        if (!removed && lane < 32 && lane >= wi) remv |= cur;
    }
    if (lane < 32) keep[(size_t)b * NWORD + lane] = ~remv;
}

// ---------------- Stage 7: stable partition (kept first) -> top-1000 gather ----------------
__global__ void k_out(const unsigned long long* __restrict__ keep,
                      const float4* __restrict__ boxes, float4* __restrict__ out) {
    int b = blockIdx.x;
    int lane = threadIdx.x;  // 64
    const unsigned long long* K = keep + (size_t)b * NWORD;
    int tot = 0;
    for (int w = 0; w < NWORD; ++w) tot += __popcll(K[w]);
    unsigned long long below = (1ull << lane) - 1ull;
    int kcum = 0, ucum = 0;
    for (int w = 0; w < NWORD; ++w) {
        unsigned long long kw = K[w];
        int pc = __popcll(kw);
        bool kept = (kw >> lane) & 1;
        int pos;
        if (kept) pos = kcum + __popcll(kw & below);
        else      pos = tot + ucum + __popcll((~kw) & below);
        if (pos < POST) out[(size_t)b * POST + pos] = boxes[(size_t)b * RANKP + w * 64 + lane];
        kcum += pc;
        ucum += 64 - pc;
    }
}

extern "C" void kernel_launch(void* const* d_in, const int* in_sizes, int n_in,
                              void* d_out, int out_size, void* d_ws, size_t ws_size,
                              hipStream_t stream) {
    const float* anchors = (const float*)d_in[0];   // [N,4]
    const float* obj     = (const float*)d_in[1];   // [B,N]
    const float* deltas  = (const float*)d_in[2];   // [B,N,4]
    char* ws = (char*)d_ws;

    uint32_t*            hist   = (uint32_t*)(ws + 0);        // B*4096*4 = 131072
    uint32_t*            cnt    = (uint32_t*)(ws + 131072);   // 256
    uint32_t*            cut    = (uint32_t*)(ws + 131328);   // 256
    unsigned long long*  cand   = (unsigned long long*)(ws + 131584);   // B*CAP*8 = 524288
    uint32_t*            topidx = (uint32_t*)(ws + 655872);   // B*2048*4 = 65536
    float4*              boxes  = (float4*)(ws + 721408);     // B*2048*16 = 524288
    unsigned long long*  valid  = (unsigned long long*)(ws + 1245696);  // B*32*8 = 2048
    unsigned long long*  sup    = (unsigned long long*)(ws + 1247744);  // B*2048*32*8 = 4194304
    unsigned long long*  keep   = (unsigned long long*)(ws + 5442048);  // 2048

    hipMemsetAsync(ws, 0, 131328, stream);  // hist + cnt

    int nchunk = (N + CHUNK - 1) / CHUNK;   // 113
    dim3 gscan(nchunk, B);
    k_hist<<<gscan, 256, 0, stream>>>(obj, hist);
    k_cut<<<B, 64, 0, stream>>>(hist, cut);
    k_compact<<<gscan, 256, 0, stream>>>(obj, cut, cnt, cand);
    k_sort<<<B, 1024, 0, stream>>>(cnt, cand, topidx);
    dim3 gdec(RANKP / 256, B);
    k_decode<<<gdec, 256, 0, stream>>>((const float4*)anchors, (const float4*)deltas,
                                       topidx, boxes, valid);
    dim3 gmask(NWORD, NWORD, B);
    k_mask<<<gmask, 64, 0, stream>>>(boxes, sup);
    k_collect<<<B, 64, 0, stream>>>(valid, sup, keep);
    k_out<<<B, 64, 0, stream>>>(keep, boxes, (float4*)d_out);
}

// Round 2
// 238.823 us; speedup vs baseline: 2.4611x; 2.4611x over previous
//
#include <hip/hip_runtime.h>
#include <stdint.h>

#define B 8
#define N 460800
#define NV4 115200          // N/4 float4 scores per image
#define PRE 2000
#define POST 1000
#define CAP 4096
#define NBIN 4096
#define RANKP 2048
#define NWORD 32
#define NMS_T 0.7f
#define XCLIP 4.135166556742356

#define SCAN_BLOCKS 45      // 45*256*10 = 115200
#define SCAN_ITER 10
#define SCAN_STRIDE (SCAN_BLOCKS * 256)

typedef unsigned long long u64;

__device__ __forceinline__ uint32_t fkey(float f) {
    uint32_t u = __float_as_uint(f);
    return (u & 0x80000000u) ? ~u : (u | 0x80000000u);
}

// ---------------- Stage 1: per-image histogram of score keys (top 12 bits) ----------------
__global__ __launch_bounds__(256) void k_hist(const float4* __restrict__ obj4,
                                              uint32_t* __restrict__ hist) {
    __shared__ uint32_t lh[2][NBIN];   // 32 KiB, 2-way replicated to cut contention
    int b = blockIdx.y;
    for (int i = threadIdx.x; i < NBIN; i += 256) { lh[0][i] = 0; lh[1][i] = 0; }
    __syncthreads();
    const float4* s = obj4 + (size_t)b * NV4;
    int t0 = blockIdx.x * 256 + threadIdx.x;
    uint32_t* h = lh[threadIdx.x & 1];
    float4 v[SCAN_ITER];
#pragma unroll
    for (int k = 0; k < SCAN_ITER; ++k) v[k] = s[t0 + k * SCAN_STRIDE];
#pragma unroll
    for (int k = 0; k < SCAN_ITER; ++k) {
        atomicAdd(&h[fkey(v[k].x) >> 20], 1u);
        atomicAdd(&h[fkey(v[k].y) >> 20], 1u);
        atomicAdd(&h[fkey(v[k].z) >> 20], 1u);
        atomicAdd(&h[fkey(v[k].w) >> 20], 1u);
    }
    __syncthreads();
    uint32_t* gh = hist + (size_t)b * NBIN;
    for (int i = threadIdx.x; i < NBIN; i += 256) {
        uint32_t s2 = lh[0][i] + lh[1][i];
        if (s2) atomicAdd(&gh[i], s2);
    }
}

// ---------------- Stage 2: find cutoff bin (2000th largest falls in it) ----------------
__global__ void k_cut(const uint32_t* __restrict__ hist, uint32_t* __restrict__ cut) {
    int b = blockIdx.x;
    int lane = threadIdx.x;  // 0..63, one wave
    const uint32_t* h = hist + (size_t)b * NBIN;
    uint32_t gs = 0;
    for (int t = 0; t < 64; ++t) gs += h[lane * 64 + t];
    uint32_t suf = gs;
    for (int d = 1; d < 64; d <<= 1) {
        uint32_t v = __shfl_down(suf, d);
        if (lane + d < 64) suf += v;
    }
    unsigned long long m = __ballot(suf >= PRE);
    int G = 63 - __clzll(m);
    uint32_t A = 0;
    if (G < 63) A = __shfl(suf, G + 1);
    uint32_t hv = h[G * 64 + lane];
    uint32_t suf2 = hv;
    for (int d = 1; d < 64; d <<= 1) {
        uint32_t v = __shfl_down(suf2, d);
        if (lane + d < 64) suf2 += v;
    }
    unsigned long long m2 = __ballot(A + suf2 >= PRE);
    int t2 = 63 - __clzll(m2);
    if (lane == 0) cut[b] = (uint32_t)(G * 64 + t2);
}

// ---------------- Stage 3: compact candidates (bin >= cut), 1 global atomic / block ------
#define LBUF 2048
__global__ __launch_bounds__(256) void k_compact(const float4* __restrict__ obj4,
                                                 const uint32_t* __restrict__ cut,
                                                 uint32_t* __restrict__ cnt,
                                                 u64* __restrict__ cand) {
    __shared__ u64 buf[LBUF];          // 16 KiB
    __shared__ uint32_t lcnt, base;
    int b = blockIdx.y;
    if (threadIdx.x == 0) lcnt = 0;
    __syncthreads();
    uint32_t cb = cut[b];
    const float4* s = obj4 + (size_t)b * NV4;
    int t0 = blockIdx.x * 256 + threadIdx.x;
    float4 v[SCAN_ITER];
#pragma unroll
    for (int k = 0; k < SCAN_ITER; ++k) v[k] = s[t0 + k * SCAN_STRIDE];
#pragma unroll
    for (int k = 0; k < SCAN_ITER; ++k) {
        int i4 = (t0 + k * SCAN_STRIDE) * 4;
        float fv[4] = {v[k].x, v[k].y, v[k].z, v[k].w};
#pragma unroll
        for (int c = 0; c < 4; ++c) {
            uint32_t key = fkey(fv[c]);
            if ((key >> 20) >= cb) {
                uint32_t p = atomicAdd(&lcnt, 1u);
                u64 e = ((u64)key << 32) | (uint32_t)(~(uint32_t)(i4 + c));
                if (p < LBUF) buf[p] = e;
                else {   // never expected; correctness fallback
                    uint32_t g = atomicAdd(&cnt[b], 1u);
                    if (g < CAP) cand[(size_t)b * CAP + g] = e;
                }
            }
        }
    }
    __syncthreads();
    uint32_t nb = lcnt < LBUF ? lcnt : LBUF;
    if (threadIdx.x == 0) base = atomicAdd(&cnt[b], nb);
    __syncthreads();
    uint32_t bs = base;
    for (uint32_t t = threadIdx.x; t < nb; t += 256) {
        uint32_t g = bs + t;
        if (g < CAP) cand[(size_t)b * CAP + g] = buf[t];
    }
}

// ---------------- Stage 4: bitonic sort candidates desc by (key, ~idx) ----------------
__global__ __launch_bounds__(1024) void k_sort(const uint32_t* __restrict__ cnt,
                                               const u64* __restrict__ cand,
                                               uint32_t* __restrict__ topidx) {
    __shared__ u64 sm[CAP];  // 32 KiB
    int b = blockIdx.x;
    uint32_t n = cnt[b]; if (n > CAP) n = CAP;
    const u64* c = cand + (size_t)b * CAP;
    for (int t = threadIdx.x; t < CAP; t += 1024) sm[t] = (t < (int)n) ? c[t] : 0ull;
    __syncthreads();
    for (unsigned k = 2; k <= CAP; k <<= 1) {
        for (unsigned j = k >> 1; j > 0; j >>= 1) {
            for (unsigned t = threadIdx.x; t < CAP; t += 1024) {
                unsigned x = t ^ j;
                if (x > t) {
                    u64 a = sm[t], bb = sm[x];
                    bool desc = ((t & k) == 0);
                    if (desc ? (a < bb) : (a > bb)) { sm[t] = bb; sm[x] = a; }
                }
            }
            __syncthreads();
        }
    }
    for (int r = threadIdx.x; r < PRE; r += 1024)
        topidx[(size_t)b * RANKP + r] = ~(uint32_t)sm[r];
}

// ---------------- Stage 5: decode + clip + small-box mask for top-2000 ----------------
__global__ void k_decode(const float4* __restrict__ anchors, const float4* __restrict__ deltas,
                         const uint32_t* __restrict__ topidx, float4* __restrict__ boxes,
                         u64* __restrict__ valid) {
    int b = blockIdx.y;
    int r = blockIdx.x * blockDim.x + threadIdx.x;  // 0..2047
    float4 out = make_float4(0.f, 0.f, 0.f, 0.f);
    bool ok = false;
    if (r < PRE) {
        uint32_t i = topidx[(size_t)b * RANKP + r];
        if (i < N) {
            float4 a = anchors[i];
            float4 d = deltas[(size_t)b * N + i];
            float w = a.z - a.x, h = a.w - a.y;
            float cx = a.x + 0.5f * w, cy = a.y + 0.5f * h;
            float dw = fminf(d.z, (float)XCLIP);
            float dh = fminf(d.w, (float)XCLIP);
            float pcx = d.x * w + cx, pcy = d.y * h + cy;
            float pw = expf(dw) * w, ph = expf(dh) * h;
            float x1 = pcx - 0.5f * pw, y1 = pcy - 0.5f * ph;
            float x2 = pcx + 0.5f * pw, y2 = pcy + 0.5f * ph;
            x1 = fminf(fmaxf(x1, 0.f), 1024.f);
            y1 = fminf(fmaxf(y1, 0.f), 1024.f);
            x2 = fminf(fmaxf(x2, 0.f), 1024.f);
            y2 = fminf(fmaxf(y2, 0.f), 1024.f);
            out = make_float4(x1, y1, x2, y2);
            ok = !((x2 - x1 < 1e-3f) || (y2 - y1 < 1e-3f));
        }
    }
    boxes[(size_t)b * RANKP + r] = out;
    u64 bal = __ballot(ok);
    if ((threadIdx.x & 63) == 0) valid[(size_t)b * NWORD + (r >> 6)] = bal;
}

// ---------------- Stage 6a: pairwise suppression bitmask ----------------
__global__ void k_mask(const float4* __restrict__ boxes, u64* __restrict__ sup) {
    int b = blockIdx.z, ti = blockIdx.y, tj = blockIdx.x;
    if (tj < ti) return;  // lower-triangle words never read
    __shared__ float4 jb[64];
    __shared__ float ja[64];
    int t = threadIdx.x;  // 64 threads
    const float4* bx = boxes + (size_t)b * RANKP;
    float4 v = bx[tj * 64 + t];
    jb[t] = v;
    ja[t] = (v.z - v.x) * (v.w - v.y);
    int i = ti * 64 + t;
    float4 bi = bx[i];
    float ai = (bi.z - bi.x) * (bi.w - bi.y);
    __syncthreads();
    u64 word = 0;
    for (int jj = 0; jj < 64; ++jj) {
        int j = tj * 64 + jj;
        float4 bj = jb[jj];
        float xx1 = fmaxf(bi.x, bj.x), yy1 = fmaxf(bi.y, bj.y);
        float xx2 = fminf(bi.z, bj.z), yy2 = fminf(bi.w, bj.w);
        float iw = fmaxf(xx2 - xx1, 0.f), ih = fmaxf(yy2 - yy1, 0.f);
        float inter = iw * ih;
        float iou = inter / (ai + ja[jj] - inter);
        if (j > i && iou > NMS_T) word |= 1ull << jj;
    }
    sup[((size_t)b * RANKP + i) * NWORD + tj] = word;
}

// ---------------- Stage 6b: sequential greedy collect, 16-deep prefetch ----------------
#define PF 16
__global__ void k_collect(const u64* __restrict__ valid,
                          const u64* __restrict__ sup,
                          u64* __restrict__ keep) {
    int b = blockIdx.x;
    int lane = threadIdx.x;  // 64
    int w = lane & 31;
    u64 remv = (lane < 32) ? ~valid[(size_t)b * NWORD + lane] : 0ull;
    const u64* S = sup + (size_t)b * RANKP * NWORD;
    u64 buf[PF];
#pragma unroll
    for (int k = 0; k < PF; ++k) buf[k] = S[(size_t)k * NWORD + w];
    for (int base = 0; base < PRE; base += PF) {
#pragma unroll
        for (int k = 0; k < PF; ++k) {
            int i = base + k;
            u64 cur = buf[k];
            buf[k] = S[(size_t)(i + PF) * NWORD + w];  // rows < RANKP always
            int wi = i >> 6;
            u64 rw = __shfl(remv, wi);
            bool removed = (rw >> (i & 63)) & 1;
            if (!removed && lane < 32 && lane >= wi) remv |= cur;
        }
    }
    if (lane < 32) keep[(size_t)b * NWORD + lane] = ~remv;
}

// ---------------- Stage 7: stable partition (kept first) -> top-1000 gather ----------------
__global__ void k_out(const u64* __restrict__ keep,
                      const float4* __restrict__ boxes, float4* __restrict__ out) {
    int b = blockIdx.x;
    int lane = threadIdx.x;  // 64
    const u64* K = keep + (size_t)b * NWORD;
    int tot = 0;
    for (int w = 0; w < NWORD; ++w) tot += __popcll(K[w]);
    u64 below = (1ull << lane) - 1ull;
    int kcum = 0, ucum = 0;
    for (int w = 0; w < NWORD; ++w) {
        u64 kw = K[w];
        int pc = __popcll(kw);
        bool kept = (kw >> lane) & 1;
        int pos;
        if (kept) pos = kcum + __popcll(kw & below);
        else      pos = tot + ucum + __popcll((~kw) & below);
        if (pos < POST) out[(size_t)b * POST + pos] = boxes[(size_t)b * RANKP + w * 64 + lane];
        kcum += pc;
        ucum += 64 - pc;
    }
}

extern "C" void kernel_launch(void* const* d_in, const int* in_sizes, int n_in,
                              void* d_out, int out_size, void* d_ws, size_t ws_size,
                              hipStream_t stream) {
    const float* anchors = (const float*)d_in[0];   // [N,4]
    const float* obj     = (const float*)d_in[1];   // [B,N]
    const float* deltas  = (const float*)d_in[2];   // [B,N,4]
    char* ws = (char*)d_ws;

    uint32_t* hist   = (uint32_t*)(ws + 0);        // 131072
    uint32_t* cnt    = (uint32_t*)(ws + 131072);   // 256
    uint32_t* cut    = (uint32_t*)(ws + 131328);   // 256
    u64*      cand   = (u64*)(ws + 131584);        // B*4096*8 = 262144 -> ends 393728
    uint32_t* topidx = (uint32_t*)(ws + 393728);   // B*2048*4 = 65536  -> 459264
    float4*   boxes  = (float4*)(ws + 459264);     // B*2048*16 = 524288 -> 983552
    u64*      valid  = (u64*)(ws + 983552);        // 2048 -> 985600
    u64*      sup    = (u64*)(ws + 985600);        // B*2048*32*8 = 4194304 -> 5179904
    u64*      keep   = (u64*)(ws + 5179904);       // 2048 -> 5181952

    hipMemsetAsync(ws, 0, 131328, stream);  // hist + cnt

    dim3 gscan(SCAN_BLOCKS, B);
    k_hist<<<gscan, 256, 0, stream>>>((const float4*)obj, hist);
    k_cut<<<B, 64, 0, stream>>>(hist, cut);
    k_compact<<<gscan, 256, 0, stream>>>((const float4*)obj, cut, cnt, cand);
    k_sort<<<B, 1024, 0, stream>>>(cnt, cand, topidx);
    dim3 gdec(RANKP / 256, B);
    k_decode<<<gdec, 256, 0, stream>>>((const float4*)anchors, (const float4*)deltas,
                                       topidx, boxes, valid);
    dim3 gmask(NWORD, NWORD, B);
    k_mask<<<gmask, 64, 0, stream>>>(boxes, sup);
    k_collect<<<B, 64, 0, stream>>>(valid, sup, keep);
    k_out<<<B, 64, 0, stream>>>(keep, boxes, (float4*)d_out);
}

// Round 4
// 215.220 us; speedup vs baseline: 2.7310x; 1.1097x over previous
//
#include <hip/hip_runtime.h>
#include <stdint.h>

#define B 8
#define N 460800
#define NV4 115200          // N/4 float4 scores per image
#define PRE 2000
#define POST 1000
#define CAP 4096
#define NBIN 4096
#define RANKP 2048
#define NWORD 32
#define NMS_T 0.7f
#define XCLIP 4.135166556742356

#define SCAN_BLOCKS 45      // 45*256*10 = 115200
#define SCAN_ITER 10
#define SCAN_STRIDE (SCAN_BLOCKS * 256)

typedef unsigned long long u64;

__device__ __forceinline__ uint32_t fkey(float f) {
    uint32_t u = __float_as_uint(f);
    return (u & 0x80000000u) ? ~u : (u | 0x80000000u);
}

__device__ __forceinline__ u64 readlane_u64(u64 v, int lane) {
    uint32_t lo = __builtin_amdgcn_readlane((uint32_t)v, lane);
    uint32_t hi = __builtin_amdgcn_readlane((uint32_t)(v >> 32), lane);
    return ((u64)hi << 32) | lo;
}

// ---------------- Stage 1: per-image histogram of score keys (top 12 bits) ----------------
__global__ __launch_bounds__(256) void k_hist(const float4* __restrict__ obj4,
                                              uint32_t* __restrict__ hist) {
    __shared__ uint32_t lh[2][NBIN];   // 32 KiB, 2-way replicated to cut contention
    int b = blockIdx.y;
    for (int i = threadIdx.x; i < NBIN; i += 256) { lh[0][i] = 0; lh[1][i] = 0; }
    __syncthreads();
    const float4* s = obj4 + (size_t)b * NV4;
    int t0 = blockIdx.x * 256 + threadIdx.x;
    uint32_t* h = lh[threadIdx.x & 1];
    float4 v[SCAN_ITER];
#pragma unroll
    for (int k = 0; k < SCAN_ITER; ++k) v[k] = s[t0 + k * SCAN_STRIDE];
#pragma unroll
    for (int k = 0; k < SCAN_ITER; ++k) {
        atomicAdd(&h[fkey(v[k].x) >> 20], 1u);
        atomicAdd(&h[fkey(v[k].y) >> 20], 1u);
        atomicAdd(&h[fkey(v[k].z) >> 20], 1u);
        atomicAdd(&h[fkey(v[k].w) >> 20], 1u);
    }
    __syncthreads();
    uint32_t* gh = hist + (size_t)b * NBIN;
    for (int i = threadIdx.x; i < NBIN; i += 256) {
        uint32_t s2 = lh[0][i] + lh[1][i];
        if (s2) atomicAdd(&gh[i], s2);
    }
}

// ---------------- Stage 2: find cutoff bin (2000th largest falls in it) ----------------
__global__ void k_cut(const uint32_t* __restrict__ hist, uint32_t* __restrict__ cut) {
    int b = blockIdx.x;
    int lane = threadIdx.x;  // 0..63, one wave
    const uint32_t* h = hist + (size_t)b * NBIN;
    uint32_t gs = 0;
    for (int t = 0; t < 64; ++t) gs += h[lane * 64 + t];
    uint32_t suf = gs;
    for (int d = 1; d < 64; d <<= 1) {
        uint32_t v = __shfl_down(suf, d);
        if (lane + d < 64) suf += v;
    }
    unsigned long long m = __ballot(suf >= PRE);
    int G = 63 - __clzll(m);
    uint32_t A = 0;
    if (G < 63) A = __shfl(suf, G + 1);
    uint32_t hv = h[G * 64 + lane];
    uint32_t suf2 = hv;
    for (int d = 1; d < 64; d <<= 1) {
        uint32_t v = __shfl_down(suf2, d);
        if (lane + d < 64) suf2 += v;
    }
    unsigned long long m2 = __ballot(A + suf2 >= PRE);
    int t2 = 63 - __clzll(m2);
    if (lane == 0) cut[b] = (uint32_t)(G * 64 + t2);
}

// ---------------- Stage 3: compact candidates (bin >= cut), 1 global atomic / block ------
#define LBUF 2048
__global__ __launch_bounds__(256) void k_compact(const float4* __restrict__ obj4,
                                                 const uint32_t* __restrict__ cut,
                                                 uint32_t* __restrict__ cnt,
                                                 u64* __restrict__ cand) {
    __shared__ u64 buf[LBUF];          // 16 KiB
    __shared__ uint32_t lcnt, base;
    int b = blockIdx.y;
    if (threadIdx.x == 0) lcnt = 0;
    __syncthreads();
    uint32_t cb = cut[b];
    const float4* s = obj4 + (size_t)b * NV4;
    int t0 = blockIdx.x * 256 + threadIdx.x;
    float4 v[SCAN_ITER];
#pragma unroll
    for (int k = 0; k < SCAN_ITER; ++k) v[k] = s[t0 + k * SCAN_STRIDE];
#pragma unroll
    for (int k = 0; k < SCAN_ITER; ++k) {
        int i4 = (t0 + k * SCAN_STRIDE) * 4;
        float fv[4] = {v[k].x, v[k].y, v[k].z, v[k].w};
#pragma unroll
        for (int c = 0; c < 4; ++c) {
            uint32_t key = fkey(fv[c]);
            if ((key >> 20) >= cb) {
                uint32_t p = atomicAdd(&lcnt, 1u);
                u64 e = ((u64)key << 32) | (uint32_t)(~(uint32_t)(i4 + c));
                if (p < LBUF) buf[p] = e;
                else {   // never expected; correctness fallback
                    uint32_t g = atomicAdd(&cnt[b], 1u);
                    if (g < CAP) cand[(size_t)b * CAP + g] = e;
                }
            }
        }
    }
    __syncthreads();
    uint32_t nb = lcnt < LBUF ? lcnt : LBUF;
    if (threadIdx.x == 0) base = atomicAdd(&cnt[b], nb);
    __syncthreads();
    uint32_t bs = base;
    for (uint32_t t = threadIdx.x; t < nb; t += 256) {
        uint32_t g = bs + t;
        if (g < CAP) cand[(size_t)b * CAP + g] = buf[t];
    }
}

// ---------------- Stage 4: bitonic sort candidates desc by (key, ~idx) ----------------
__global__ __launch_bounds__(1024) void k_sort(const uint32_t* __restrict__ cnt,
                                               const u64* __restrict__ cand,
                                               uint32_t* __restrict__ topidx) {
    __shared__ u64 sm[CAP];  // 32 KiB
    int b = blockIdx.x;
    uint32_t n = cnt[b]; if (n > CAP) n = CAP;
    const u64* c = cand + (size_t)b * CAP;
    for (int t = threadIdx.x; t < CAP; t += 1024) sm[t] = (t < (int)n) ? c[t] : 0ull;
    __syncthreads();
    for (unsigned k = 2; k <= CAP; k <<= 1) {
        for (unsigned j = k >> 1; j > 0; j >>= 1) {
            for (unsigned t = threadIdx.x; t < CAP; t += 1024) {
                unsigned x = t ^ j;
                if (x > t) {
                    u64 a = sm[t], bb = sm[x];
                    bool desc = ((t & k) == 0);
                    if (desc ? (a < bb) : (a > bb)) { sm[t] = bb; sm[x] = a; }
                }
            }
            __syncthreads();
        }
    }
    for (int r = threadIdx.x; r < PRE; r += 1024)
        topidx[(size_t)b * RANKP + r] = ~(uint32_t)sm[r];
}

// ---------------- Stage 5: decode + clip + small-box mask for top-2000 ----------------
__global__ void k_decode(const float4* __restrict__ anchors, const float4* __restrict__ deltas,
                         const uint32_t* __restrict__ topidx, float4* __restrict__ boxes,
                         u64* __restrict__ valid) {
    int b = blockIdx.y;
    int r = blockIdx.x * blockDim.x + threadIdx.x;  // 0..2047
    float4 out = make_float4(0.f, 0.f, 0.f, 0.f);
    bool ok = false;
    if (r < PRE) {
        uint32_t i = topidx[(size_t)b * RANKP + r];
        if (i < N) {
            float4 a = anchors[i];
            float4 d = deltas[(size_t)b * N + i];
            float w = a.z - a.x, h = a.w - a.y;
            float cx = a.x + 0.5f * w, cy = a.y + 0.5f * h;
            float dw = fminf(d.z, (float)XCLIP);
            float dh = fminf(d.w, (float)XCLIP);
            float pcx = d.x * w + cx, pcy = d.y * h + cy;
            float pw = expf(dw) * w, ph = expf(dh) * h;
            float x1 = pcx - 0.5f * pw, y1 = pcy - 0.5f * ph;
            float x2 = pcx + 0.5f * pw, y2 = pcy + 0.5f * ph;
            x1 = fminf(fmaxf(x1, 0.f), 1024.f);
            y1 = fminf(fmaxf(y1, 0.f), 1024.f);
            x2 = fminf(fmaxf(x2, 0.f), 1024.f);
            y2 = fminf(fmaxf(y2, 0.f), 1024.f);
            out = make_float4(x1, y1, x2, y2);
            ok = !((x2 - x1 < 1e-3f) || (y2 - y1 < 1e-3f));
        }
    }
    boxes[(size_t)b * RANKP + r] = out;
    u64 bal = __ballot(ok);
    if ((threadIdx.x & 63) == 0) valid[(size_t)b * NWORD + (r >> 6)] = bal;
}

// ---------------- Stage 6a: pairwise suppression bitmask (triangular grid) ----------------
#define NTRI (NWORD * (NWORD + 1) / 2)   // 528
__global__ void k_mask(const float4* __restrict__ boxes, u64* __restrict__ sup) {
    int b = blockIdx.y;
    // map linear upper-triangle index -> (ti, tj), tj >= ti
    int L = blockIdx.x;
    int ti = 0, rem = L;
    while (rem >= NWORD - ti) { rem -= NWORD - ti; ++ti; }
    int tj = ti + rem;
    __shared__ float4 jb[64];
    __shared__ float ja[64];
    int t = threadIdx.x;  // 64 threads
    const float4* bx = boxes + (size_t)b * RANKP;
    float4 v = bx[tj * 64 + t];
    jb[t] = v;
    ja[t] = (v.z - v.x) * (v.w - v.y);
    int i = ti * 64 + t;
    float4 bi = bx[i];
    float ai = (bi.z - bi.x) * (bi.w - bi.y);
    __syncthreads();
    u64 word = 0;
    for (int jj = 0; jj < 64; ++jj) {
        int j = tj * 64 + jj;
        float4 bj = jb[jj];
        float xx1 = fmaxf(bi.x, bj.x), yy1 = fmaxf(bi.y, bj.y);
        float xx2 = fminf(bi.z, bj.z), yy2 = fminf(bi.w, bj.w);
        float iw = fmaxf(xx2 - xx1, 0.f), ih = fmaxf(yy2 - yy1, 0.f);
        float inter = iw * ih;
        float iou = inter / (ai + ja[jj] - inter);
        if (j > i && iou > NMS_T) word |= 1ull << jj;
    }
    sup[((size_t)b * RANKP + i) * NWORD + tj] = word;
}

// ---------------- Stage 6b: sequential greedy collect, scalar chain + 64-deep prefetch ----
// NOTE: sup's lower-triangle words (tj < ti) are NEVER written (0xAA poison from the
// harness) — the `lane >= wi` guard below keeps them out of remv. Do not remove it.
#define PF 64
__global__ __launch_bounds__(64) void k_collect(const u64* __restrict__ valid,
                                                const u64* __restrict__ sup,
                                                u64* __restrict__ keep) {
    int b = blockIdx.x;
    int lane = threadIdx.x;  // 64
    int w = lane & 31;
    u64 remv = (lane < 32) ? ~valid[(size_t)b * NWORD + lane] : 0ull;
    const u64* S = sup + (size_t)b * RANKP * NWORD;
    u64 buf[PF];
#pragma unroll
    for (int k = 0; k < PF; ++k) buf[k] = S[(size_t)k * NWORD + w];
    // rows 2000..2047: zero boxes -> NaN IoU -> all-zero sup rows; their valid bits are
    // 0 so they're skipped. Processing them is harmless; loop in 64-chunks.
    for (int base = 0; base < RANKP; base += PF) {
        int wi = base >> 6;                       // word under test, constant per chunk
        u64 scur = readlane_u64(remv, wi);        // wave-uniform copy of remv[wi]
#pragma unroll
        for (int k = 0; k < PF; ++k) {
            int i = base + k;
            u64 cur = buf[k];
            buf[k] = S[(size_t)((i + PF) & (RANKP - 1)) * NWORD + w];
            bool removed = (scur >> (i & 63)) & 1ull;
            if (!removed) {                        // wave-uniform branch (scur is scalar)
                if (lane >= wi) remv |= cur;       // only valid (written) words; guard
                                                   // also excludes poisoned tj<ti words
                scur |= readlane_u64(cur, wi);     // scalar side (current word)
            }
        }
    }
    if (lane < 32) keep[(size_t)b * NWORD + lane] = ~remv;
}

// ---------------- Stage 7: stable partition (kept first) -> top-1000 gather ----------------
__global__ void k_out(const u64* __restrict__ keep,
                      const float4* __restrict__ boxes, float4* __restrict__ out) {
    int b = blockIdx.x;
    int lane = threadIdx.x;  // 64
    const u64* K = keep + (size_t)b * NWORD;
    int tot = 0;
    for (int w = 0; w < NWORD; ++w) tot += __popcll(K[w]);
    u64 below = (1ull << lane) - 1ull;
    int kcum = 0, ucum = 0;
    for (int w = 0; w < NWORD; ++w) {
        u64 kw = K[w];
        int pc = __popcll(kw);
        bool kept = (kw >> lane) & 1;
        int pos;
        if (kept) pos = kcum + __popcll(kw & below);
        else      pos = tot + ucum + __popcll((~kw) & below);
        if (pos < POST) out[(size_t)b * POST + pos] = boxes[(size_t)b * RANKP + w * 64 + lane];
        kcum += pc;
        ucum += 64 - pc;
    }
}

extern "C" void kernel_launch(void* const* d_in, const int* in_sizes, int n_in,
                              void* d_out, int out_size, void* d_ws, size_t ws_size,
                              hipStream_t stream) {
    const float* anchors = (const float*)d_in[0];   // [N,4]
    const float* obj     = (const float*)d_in[1];   // [B,N]
    const float* deltas  = (const float*)d_in[2];   // [B,N,4]
    char* ws = (char*)d_ws;

    uint32_t* hist   = (uint32_t*)(ws + 0);        // 131072
    uint32_t* cnt    = (uint32_t*)(ws + 131072);   // 256
    uint32_t* cut    = (uint32_t*)(ws + 131328);   // 256
    u64*      cand   = (u64*)(ws + 131584);        // B*4096*8 = 262144 -> 393728
    uint32_t* topidx = (uint32_t*)(ws + 393728);   // B*2048*4 = 65536  -> 459264
    float4*   boxes  = (float4*)(ws + 459264);     // B*2048*16 = 524288 -> 983552
    u64*      valid  = (u64*)(ws + 983552);        // 2048 -> 985600
    u64*      sup    = (u64*)(ws + 985600);        // B*2048*32*8 = 4194304 -> 5179904
    u64*      keep   = (u64*)(ws + 5179904);       // 2048 -> 5181952

    hipMemsetAsync(ws, 0, 131328, stream);  // hist + cnt

    dim3 gscan(SCAN_BLOCKS, B);
    k_hist<<<gscan, 256, 0, stream>>>((const float4*)obj, hist);
    k_cut<<<B, 64, 0, stream>>>(hist, cut);
    k_compact<<<gscan, 256, 0, stream>>>((const float4*)obj, cut, cnt, cand);
    k_sort<<<B, 1024, 0, stream>>>(cnt, cand, topidx);
    dim3 gdec(RANKP / 256, B);
    k_decode<<<gdec, 256, 0, stream>>>((const float4*)anchors, (const float4*)deltas,
                                       topidx, boxes, valid);
    dim3 gmask(NTRI, B);
    k_mask<<<gmask, 64, 0, stream>>>(boxes, sup);
    k_collect<<<B, 64, 0, stream>>>(valid, sup, keep);
    k_out<<<B, 64, 0, stream>>>(keep, boxes, (float4*)d_out);
}

// Round 5
// 185.674 us; speedup vs baseline: 3.1656x; 1.1591x over previous
//
#include <hip/hip_runtime.h>
#include <stdint.h>

#define B 8
#define N 460800
#define NV4 115200          // N/4 float4 scores per image
#define PRE 2000
#define POST 1000
#define CAP 4096
#define NBIN 4096
#define RANKP 2048
#define NWORD 32
#define NMS_T 0.7f
#define XCLIP 4.135166556742356

#define SCAN_BLOCKS 45      // 45*256*10 = 115200
#define SCAN_ITER 10
#define SCAN_STRIDE (SCAN_BLOCKS * 256)

typedef unsigned long long u64;

__device__ __forceinline__ uint32_t fkey(float f) {
    uint32_t u = __float_as_uint(f);
    return (u & 0x80000000u) ? ~u : (u | 0x80000000u);
}

__device__ __forceinline__ u64 readlane_u64(u64 v, int lane) {
    uint32_t lo = __builtin_amdgcn_readlane((uint32_t)v, lane);
    uint32_t hi = __builtin_amdgcn_readlane((uint32_t)(v >> 32), lane);
    return ((u64)hi << 32) | lo;
}

// ---------------- Stage 1: per-image histogram of score keys (top 12 bits) ----------------
__global__ __launch_bounds__(256) void k_hist(const float4* __restrict__ obj4,
                                              uint32_t* __restrict__ hist) {
    __shared__ uint32_t lh[2][NBIN];   // 32 KiB, 2-way replicated to cut contention
    int b = blockIdx.y;
    for (int i = threadIdx.x; i < NBIN; i += 256) { lh[0][i] = 0; lh[1][i] = 0; }
    __syncthreads();
    const float4* s = obj4 + (size_t)b * NV4;
    int t0 = blockIdx.x * 256 + threadIdx.x;
    uint32_t* h = lh[threadIdx.x & 1];
    float4 v[SCAN_ITER];
#pragma unroll
    for (int k = 0; k < SCAN_ITER; ++k) v[k] = s[t0 + k * SCAN_STRIDE];
#pragma unroll
    for (int k = 0; k < SCAN_ITER; ++k) {
        atomicAdd(&h[fkey(v[k].x) >> 20], 1u);
        atomicAdd(&h[fkey(v[k].y) >> 20], 1u);
        atomicAdd(&h[fkey(v[k].z) >> 20], 1u);
        atomicAdd(&h[fkey(v[k].w) >> 20], 1u);
    }
    __syncthreads();
    uint32_t* gh = hist + (size_t)b * NBIN;
    for (int i = threadIdx.x; i < NBIN; i += 256) {
        uint32_t s2 = lh[0][i] + lh[1][i];
        if (s2) atomicAdd(&gh[i], s2);
    }
}

// ---------------- Stage 2: find cutoff bin (2000th largest falls in it) ----------------
__global__ void k_cut(const uint32_t* __restrict__ hist, uint32_t* __restrict__ cut) {
    int b = blockIdx.x;
    int lane = threadIdx.x;  // 0..63, one wave
    const uint32_t* h = hist + (size_t)b * NBIN;
    uint32_t gs = 0;
    for (int t = 0; t < 64; ++t) gs += h[lane * 64 + t];
    uint32_t suf = gs;
    for (int d = 1; d < 64; d <<= 1) {
        uint32_t v = __shfl_down(suf, d);
        if (lane + d < 64) suf += v;
    }
    unsigned long long m = __ballot(suf >= PRE);
    int G = 63 - __clzll(m);
    uint32_t A = 0;
    if (G < 63) A = __shfl(suf, G + 1);
    uint32_t hv = h[G * 64 + lane];
    uint32_t suf2 = hv;
    for (int d = 1; d < 64; d <<= 1) {
        uint32_t v = __shfl_down(suf2, d);
        if (lane + d < 64) suf2 += v;
    }
    unsigned long long m2 = __ballot(A + suf2 >= PRE);
    int t2 = 63 - __clzll(m2);
    if (lane == 0) cut[b] = (uint32_t)(G * 64 + t2);
}

// ---------------- Stage 3: compact candidates (bin >= cut), 1 global atomic / block ------
#define LBUF 2048
__global__ __launch_bounds__(256) void k_compact(const float4* __restrict__ obj4,
                                                 const uint32_t* __restrict__ cut,
                                                 uint32_t* __restrict__ cnt,
                                                 u64* __restrict__ cand) {
    __shared__ u64 buf[LBUF];          // 16 KiB
    __shared__ uint32_t lcnt, base;
    int b = blockIdx.y;
    if (threadIdx.x == 0) lcnt = 0;
    __syncthreads();
    uint32_t cb = cut[b];
    const float4* s = obj4 + (size_t)b * NV4;
    int t0 = blockIdx.x * 256 + threadIdx.x;
    float4 v[SCAN_ITER];
#pragma unroll
    for (int k = 0; k < SCAN_ITER; ++k) v[k] = s[t0 + k * SCAN_STRIDE];
#pragma unroll
    for (int k = 0; k < SCAN_ITER; ++k) {
        int i4 = (t0 + k * SCAN_STRIDE) * 4;
        float fv[4] = {v[k].x, v[k].y, v[k].z, v[k].w};
#pragma unroll
        for (int c = 0; c < 4; ++c) {
            uint32_t key = fkey(fv[c]);
            if ((key >> 20) >= cb) {
                uint32_t p = atomicAdd(&lcnt, 1u);
                u64 e = ((u64)key << 32) | (uint32_t)(~(uint32_t)(i4 + c));
                if (p < LBUF) buf[p] = e;
                else {   // never expected; correctness fallback
                    uint32_t g = atomicAdd(&cnt[b], 1u);
                    if (g < CAP) cand[(size_t)b * CAP + g] = e;
                }
            }
        }
    }
    __syncthreads();
    uint32_t nb = lcnt < LBUF ? lcnt : LBUF;
    if (threadIdx.x == 0) base = atomicAdd(&cnt[b], nb);
    __syncthreads();
    uint32_t bs = base;
    for (uint32_t t = threadIdx.x; t < nb; t += 256) {
        uint32_t g = bs + t;
        if (g < CAP) cand[(size_t)b * CAP + g] = buf[t];
    }
}

// ---------------- Stage 4: bitonic sort candidates desc by (key, ~idx) ----------------
__global__ __launch_bounds__(1024) void k_sort(const uint32_t* __restrict__ cnt,
                                               const u64* __restrict__ cand,
                                               uint32_t* __restrict__ topidx) {
    __shared__ u64 sm[CAP];  // 32 KiB
    int b = blockIdx.x;
    uint32_t n = cnt[b]; if (n > CAP) n = CAP;
    const u64* c = cand + (size_t)b * CAP;
    for (int t = threadIdx.x; t < CAP; t += 1024) sm[t] = (t < (int)n) ? c[t] : 0ull;
    __syncthreads();
    for (unsigned k = 2; k <= CAP; k <<= 1) {
        for (unsigned j = k >> 1; j > 0; j >>= 1) {
            for (unsigned t = threadIdx.x; t < CAP; t += 1024) {
                unsigned x = t ^ j;
                if (x > t) {
                    u64 a = sm[t], bb = sm[x];
                    bool desc = ((t & k) == 0);
                    if (desc ? (a < bb) : (a > bb)) { sm[t] = bb; sm[x] = a; }
                }
            }
            __syncthreads();
        }
    }
    for (int r = threadIdx.x; r < PRE; r += 1024)
        topidx[(size_t)b * RANKP + r] = ~(uint32_t)sm[r];
}

// ---------------- Stage 5: decode + clip + small-box mask for top-2000 ----------------
__global__ void k_decode(const float4* __restrict__ anchors, const float4* __restrict__ deltas,
                         const uint32_t* __restrict__ topidx, float4* __restrict__ boxes,
                         u64* __restrict__ valid) {
    int b = blockIdx.y;
    int r = blockIdx.x * blockDim.x + threadIdx.x;  // 0..2047
    float4 out = make_float4(0.f, 0.f, 0.f, 0.f);
    bool ok = false;
    if (r < PRE) {
        uint32_t i = topidx[(size_t)b * RANKP + r];
        if (i < N) {
            float4 a = anchors[i];
            float4 d = deltas[(size_t)b * N + i];
            float w = a.z - a.x, h = a.w - a.y;
            float cx = a.x + 0.5f * w, cy = a.y + 0.5f * h;
            float dw = fminf(d.z, (float)XCLIP);
            float dh = fminf(d.w, (float)XCLIP);
            float pcx = d.x * w + cx, pcy = d.y * h + cy;
            float pw = expf(dw) * w, ph = expf(dh) * h;
            float x1 = pcx - 0.5f * pw, y1 = pcy - 0.5f * ph;
            float x2 = pcx + 0.5f * pw, y2 = pcy + 0.5f * ph;
            x1 = fminf(fmaxf(x1, 0.f), 1024.f);
            y1 = fminf(fmaxf(y1, 0.f), 1024.f);
            x2 = fminf(fmaxf(x2, 0.f), 1024.f);
            y2 = fminf(fmaxf(y2, 0.f), 1024.f);
            out = make_float4(x1, y1, x2, y2);
            ok = !((x2 - x1 < 1e-3f) || (y2 - y1 < 1e-3f));
        }
    }
    boxes[(size_t)b * RANKP + r] = out;
    u64 bal = __ballot(ok);
    if ((threadIdx.x & 63) == 0) valid[(size_t)b * NWORD + (r >> 6)] = bal;
}

// ---------------- Stage 6a: pairwise suppression bitmask (triangular grid) ----------------
#define NTRI (NWORD * (NWORD + 1) / 2)   // 528
__global__ void k_mask(const float4* __restrict__ boxes, u64* __restrict__ sup) {
    int b = blockIdx.y;
    int L = blockIdx.x;
    int ti = 0, rem = L;
    while (rem >= NWORD - ti) { rem -= NWORD - ti; ++ti; }
    int tj = ti + rem;
    __shared__ float4 jb[64];
    __shared__ float ja[64];
    int t = threadIdx.x;  // 64 threads
    const float4* bx = boxes + (size_t)b * RANKP;
    float4 v = bx[tj * 64 + t];
    jb[t] = v;
    ja[t] = (v.z - v.x) * (v.w - v.y);
    int i = ti * 64 + t;
    float4 bi = bx[i];
    float ai = (bi.z - bi.x) * (bi.w - bi.y);
    __syncthreads();
    u64 word = 0;
    for (int jj = 0; jj < 64; ++jj) {
        int j = tj * 64 + jj;
        float4 bj = jb[jj];
        float xx1 = fmaxf(bi.x, bj.x), yy1 = fmaxf(bi.y, bj.y);
        float xx2 = fminf(bi.z, bj.z), yy2 = fminf(bi.w, bj.w);
        float iw = fmaxf(xx2 - xx1, 0.f), ih = fmaxf(yy2 - yy1, 0.f);
        float inter = iw * ih;
        float iou = inter / (ai + ja[jj] - inter);
        if (j > i && iou > NMS_T) word |= 1ull << jj;
    }
    sup[((size_t)b * RANKP + i) * NWORD + tj] = word;
}

// ---------------- Stage 6b+7: chunked greedy NMS + stable-partition output ----------------
// Per 64-row chunk c: step1 = serial recurrence on the DIAGONAL tile only (registers,
// scalar chain, no loads); step2 = parallel OR of kept rows' full sup rows into remv.
// sup lower-triangle words (w < row's chunk) are NEVER written (0xAA poison) — the
// `lane >= c` guard keeps them out of remv. Do not remove it.
// Early exit once kept count >= POST: all output positions < POST are then final.
__global__ __launch_bounds__(64) void k_nms(const u64* __restrict__ valid,
                                            const u64* __restrict__ sup,
                                            const float4* __restrict__ boxes,
                                            float4* __restrict__ out) {
    int b = blockIdx.x;
    int lane = threadIdx.x;           // 64
    int w = lane & 31, hh = lane >> 5;
    const u64* S = sup + (size_t)b * RANKP * NWORD;
    u64 remv = (lane < 32) ? ~valid[(size_t)b * NWORD + lane] : 0ull;
    // D for chunk 0: lane i -> diag word S[row i][0]
    u64 D = S[(size_t)lane * NWORD + 0];
    int kept_cnt = 0;
    for (int c = 0; c < NWORD; ++c) {
        int base = c * 64;
        // issue this chunk's row loads (lane: word w, rows hh*32..hh*32+31)
        u64 rowv[32];
#pragma unroll
        for (int r = 0; r < 32; ++r)
            rowv[r] = S[(size_t)(base + hh * 32 + r) * NWORD + w];
        // issue next chunk's diagonal words (wraps at c=31; unused then)
        int cn = (c + 1) & (NWORD - 1);
        u64 Dn = S[(size_t)(cn * 64 + lane) * NWORD + cn];
        // ---- step1: serial scalar recurrence on diagonal tile ----
        u64 scur = readlane_u64(remv, c);
#pragma unroll
        for (int i = 0; i < 64; ++i) {
            u64 d = readlane_u64(D, i);
            if (!((scur >> i) & 1ull)) scur |= d;   // uniform: s_cselect/s_or
        }
        u64 kept = ~scur;
        // ---- step2: OR kept rows into remv (parallel, branchless) ----
        u64 acc = 0;
#pragma unroll
        for (int r = 0; r < 32; ++r) {
            u64 m = ((kept >> (hh * 32 + r)) & 1ull) ? ~0ull : 0ull;  // scalar mask
            acc |= rowv[r] & m;
        }
        u64 acco = __shfl(acc, lane + 32);   // partner half's accumulation
        if (lane < 32 && lane >= c) remv |= (acc | acco);
        kept_cnt += (int)__popcll(kept);
        D = Dn;
        if (kept_cnt >= POST) break;
    }
    // ---- epilogue: stable partition (kept first) -> top-1000 gather ----
    int tot = 0;
    for (int ww = 0; ww < NWORD; ++ww)
        tot += (int)__popcll(~readlane_u64(remv, ww));
    u64 below = (1ull << lane) - 1ull;
    int kcum = 0, ucum = 0;
    for (int ww = 0; ww < NWORD; ++ww) {
        u64 kw = ~readlane_u64(remv, ww);
        int pc = (int)__popcll(kw);
        bool kp = (kw >> lane) & 1ull;
        int pos;
        if (kp) pos = kcum + (int)__popcll(kw & below);
        else    pos = tot + ucum + (int)__popcll((~kw) & below);
        if (pos < POST) out[(size_t)b * POST + pos] = boxes[(size_t)b * RANKP + ww * 64 + lane];
        kcum += pc;
        ucum += 64 - pc;
    }
}

extern "C" void kernel_launch(void* const* d_in, const int* in_sizes, int n_in,
                              void* d_out, int out_size, void* d_ws, size_t ws_size,
                              hipStream_t stream) {
    const float* anchors = (const float*)d_in[0];   // [N,4]
    const float* obj     = (const float*)d_in[1];   // [B,N]
    const float* deltas  = (const float*)d_in[2];   // [B,N,4]
    char* ws = (char*)d_ws;

    uint32_t* hist   = (uint32_t*)(ws + 0);        // 131072
    uint32_t* cnt    = (uint32_t*)(ws + 131072);   // 256
    uint32_t* cut    = (uint32_t*)(ws + 131328);   // 256
    u64*      cand   = (u64*)(ws + 131584);        // B*4096*8 = 262144 -> 393728
    uint32_t* topidx = (uint32_t*)(ws + 393728);   // B*2048*4 = 65536  -> 459264
    float4*   boxes  = (float4*)(ws + 459264);     // B*2048*16 = 524288 -> 983552
    u64*      valid  = (u64*)(ws + 983552);        // 2048 -> 985600
    u64*      sup    = (u64*)(ws + 985600);        // B*2048*32*8 = 4194304 -> 5179904

    hipMemsetAsync(ws, 0, 131328, stream);  // hist + cnt

    dim3 gscan(SCAN_BLOCKS, B);
    k_hist<<<gscan, 256, 0, stream>>>((const float4*)obj, hist);
    k_cut<<<B, 64, 0, stream>>>(hist, cut);
    k_compact<<<gscan, 256, 0, stream>>>((const float4*)obj, cut, cnt, cand);
    k_sort<<<B, 1024, 0, stream>>>(cnt, cand, topidx);
    dim3 gdec(RANKP / 256, B);
    k_decode<<<gdec, 256, 0, stream>>>((const float4*)anchors, (const float4*)deltas,
                                       topidx, boxes, valid);
    dim3 gmask(NTRI, B);
    k_mask<<<gmask, 64, 0, stream>>>(boxes, sup);
    k_nms<<<B, 64, 0, stream>>>(valid, sup, boxes, (float4*)d_out);
}

// Round 6
// 153.549 us; speedup vs baseline: 3.8279x; 1.2092x over previous
//
#include <hip/hip_runtime.h>
#include <stdint.h>

#define B 8
#define N 460800
#define NV4 115200          // N/4 float4 scores per image
#define PRE 2000
#define POST 1000
#define CAP 4096
#define NBIN 4096
#define RANKP 2048
#define NWORD 32
#define NMS_T 0.7f
#define XCLIP 4.135166556742356

#define SCAN_BLOCKS 45      // 45*256*10 = 115200
#define SCAN_ITER 10
#define SCAN_STRIDE (SCAN_BLOCKS * 256)

typedef unsigned long long u64;

__device__ __forceinline__ uint32_t fkey(float f) {
    uint32_t u = __float_as_uint(f);
    return (u & 0x80000000u) ? ~u : (u | 0x80000000u);
}

__device__ __forceinline__ u64 readlane_u64(u64 v, int lane) {
    uint32_t lo = __builtin_amdgcn_readlane((uint32_t)v, lane);
    uint32_t hi = __builtin_amdgcn_readlane((uint32_t)(v >> 32), lane);
    return ((u64)hi << 32) | lo;
}

// ---------------- Stage 1: per-image histogram of score keys (top 12 bits) ----------------
__global__ __launch_bounds__(256) void k_hist(const float4* __restrict__ obj4,
                                              uint32_t* __restrict__ hist) {
    __shared__ uint32_t lh[2][NBIN];   // 32 KiB, 2-way replicated to cut contention
    int b = blockIdx.y;
    for (int i = threadIdx.x; i < NBIN; i += 256) { lh[0][i] = 0; lh[1][i] = 0; }
    __syncthreads();
    const float4* s = obj4 + (size_t)b * NV4;
    int t0 = blockIdx.x * 256 + threadIdx.x;
    uint32_t* h = lh[threadIdx.x & 1];
    float4 v[SCAN_ITER];
#pragma unroll
    for (int k = 0; k < SCAN_ITER; ++k) v[k] = s[t0 + k * SCAN_STRIDE];
#pragma unroll
    for (int k = 0; k < SCAN_ITER; ++k) {
        atomicAdd(&h[fkey(v[k].x) >> 20], 1u);
        atomicAdd(&h[fkey(v[k].y) >> 20], 1u);
        atomicAdd(&h[fkey(v[k].z) >> 20], 1u);
        atomicAdd(&h[fkey(v[k].w) >> 20], 1u);
    }
    __syncthreads();
    uint32_t* gh = hist + (size_t)b * NBIN;
    for (int i = threadIdx.x; i < NBIN; i += 256) {
        uint32_t s2 = lh[0][i] + lh[1][i];
        if (s2) atomicAdd(&gh[i], s2);
    }
}

// ---------------- Stage 2: find cutoff bin (2000th largest falls in it) ----------------
__global__ void k_cut(const uint32_t* __restrict__ hist, uint32_t* __restrict__ cut) {
    int b = blockIdx.x;
    int lane = threadIdx.x;  // 0..63, one wave
    const uint32_t* h = hist + (size_t)b * NBIN;
    uint32_t gs = 0;
    for (int t = 0; t < 64; ++t) gs += h[lane * 64 + t];
    uint32_t suf = gs;
    for (int d = 1; d < 64; d <<= 1) {
        uint32_t v = __shfl_down(suf, d);
        if (lane + d < 64) suf += v;
    }
    unsigned long long m = __ballot(suf >= PRE);
    int G = 63 - __clzll(m);
    uint32_t A = 0;
    if (G < 63) A = __shfl(suf, G + 1);
    uint32_t hv = h[G * 64 + lane];
    uint32_t suf2 = hv;
    for (int d = 1; d < 64; d <<= 1) {
        uint32_t v = __shfl_down(suf2, d);
        if (lane + d < 64) suf2 += v;
    }
    unsigned long long m2 = __ballot(A + suf2 >= PRE);
    int t2 = 63 - __clzll(m2);
    if (lane == 0) cut[b] = (uint32_t)(G * 64 + t2);
}

// ---------------- Stage 3: compact candidates (bin >= cut), 1 global atomic / block ------
#define LBUF 2048
__global__ __launch_bounds__(256) void k_compact(const float4* __restrict__ obj4,
                                                 const uint32_t* __restrict__ cut,
                                                 uint32_t* __restrict__ cnt,
                                                 u64* __restrict__ cand) {
    __shared__ u64 buf[LBUF];          // 16 KiB
    __shared__ uint32_t lcnt, base;
    int b = blockIdx.y;
    if (threadIdx.x == 0) lcnt = 0;
    __syncthreads();
    uint32_t cb = cut[b];
    const float4* s = obj4 + (size_t)b * NV4;
    int t0 = blockIdx.x * 256 + threadIdx.x;
    float4 v[SCAN_ITER];
#pragma unroll
    for (int k = 0; k < SCAN_ITER; ++k) v[k] = s[t0 + k * SCAN_STRIDE];
#pragma unroll
    for (int k = 0; k < SCAN_ITER; ++k) {
        int i4 = (t0 + k * SCAN_STRIDE) * 4;
        float fv[4] = {v[k].x, v[k].y, v[k].z, v[k].w};
#pragma unroll
        for (int c = 0; c < 4; ++c) {
            uint32_t key = fkey(fv[c]);
            if ((key >> 20) >= cb) {
                uint32_t p = atomicAdd(&lcnt, 1u);
                u64 e = ((u64)key << 32) | (uint32_t)(~(uint32_t)(i4 + c));
                if (p < LBUF) buf[p] = e;
                else {   // never expected; correctness fallback
                    uint32_t g = atomicAdd(&cnt[b], 1u);
                    if (g < CAP) cand[(size_t)b * CAP + g] = e;
                }
            }
        }
    }
    __syncthreads();
    uint32_t nb = lcnt < LBUF ? lcnt : LBUF;
    if (threadIdx.x == 0) base = atomicAdd(&cnt[b], nb);
    __syncthreads();
    uint32_t bs = base;
    for (uint32_t t = threadIdx.x; t < nb; t += 256) {
        uint32_t g = bs + t;
        if (g < CAP) cand[(size_t)b * CAP + g] = buf[t];
    }
}

// ---------------- Stage 4: bitonic sort candidates desc by (key, ~idx) ----------------
__global__ __launch_bounds__(1024) void k_sort(const uint32_t* __restrict__ cnt,
                                               const u64* __restrict__ cand,
                                               uint32_t* __restrict__ topidx) {
    __shared__ u64 sm[CAP];  // 32 KiB
    int b = blockIdx.x;
    uint32_t n = cnt[b]; if (n > CAP) n = CAP;
    const u64* c = cand + (size_t)b * CAP;
    for (int t = threadIdx.x; t < CAP; t += 1024) sm[t] = (t < (int)n) ? c[t] : 0ull;
    __syncthreads();
    for (unsigned k = 2; k <= CAP; k <<= 1) {
        for (unsigned j = k >> 1; j > 0; j >>= 1) {
            for (unsigned t = threadIdx.x; t < CAP; t += 1024) {
                unsigned x = t ^ j;
                if (x > t) {
                    u64 a = sm[t], bb = sm[x];
                    bool desc = ((t & k) == 0);
                    if (desc ? (a < bb) : (a > bb)) { sm[t] = bb; sm[x] = a; }
                }
            }
            __syncthreads();
        }
    }
    for (int r = threadIdx.x; r < PRE; r += 1024)
        topidx[(size_t)b * RANKP + r] = ~(uint32_t)sm[r];
}

// ---------------- Stage 5: decode + clip + small-box mask for top-2000 ----------------
__global__ void k_decode(const float4* __restrict__ anchors, const float4* __restrict__ deltas,
                         const uint32_t* __restrict__ topidx, float4* __restrict__ boxes,
                         u64* __restrict__ valid) {
    int b = blockIdx.y;
    int r = blockIdx.x * blockDim.x + threadIdx.x;  // 0..2047
    float4 out = make_float4(0.f, 0.f, 0.f, 0.f);
    bool ok = false;
    if (r < PRE) {
        uint32_t i = topidx[(size_t)b * RANKP + r];
        if (i < N) {
            float4 a = anchors[i];
            float4 d = deltas[(size_t)b * N + i];
            float w = a.z - a.x, h = a.w - a.y;
            float cx = a.x + 0.5f * w, cy = a.y + 0.5f * h;
            float dw = fminf(d.z, (float)XCLIP);
            float dh = fminf(d.w, (float)XCLIP);
            float pcx = d.x * w + cx, pcy = d.y * h + cy;
            float pw = expf(dw) * w, ph = expf(dh) * h;
            float x1 = pcx - 0.5f * pw, y1 = pcy - 0.5f * ph;
            float x2 = pcx + 0.5f * pw, y2 = pcy + 0.5f * ph;
            x1 = fminf(fmaxf(x1, 0.f), 1024.f);
            y1 = fminf(fmaxf(y1, 0.f), 1024.f);
            x2 = fminf(fmaxf(x2, 0.f), 1024.f);
            y2 = fminf(fmaxf(y2, 0.f), 1024.f);
            out = make_float4(x1, y1, x2, y2);
            ok = !((x2 - x1 < 1e-3f) || (y2 - y1 < 1e-3f));
        }
    }
    boxes[(size_t)b * RANKP + r] = out;
    u64 bal = __ballot(ok);
    if ((threadIdx.x & 63) == 0) valid[(size_t)b * NWORD + (r >> 6)] = bal;
}

// ---------------- Stage 6a: pairwise suppression bitmask (triangular grid) ----------------
#define NTRI (NWORD * (NWORD + 1) / 2)   // 528
__global__ void k_mask(const float4* __restrict__ boxes, u64* __restrict__ sup) {
    int b = blockIdx.y;
    int L = blockIdx.x;
    int ti = 0, rem = L;
    while (rem >= NWORD - ti) { rem -= NWORD - ti; ++ti; }
    int tj = ti + rem;
    __shared__ float4 jb[64];
    __shared__ float ja[64];
    int t = threadIdx.x;  // 64 threads
    const float4* bx = boxes + (size_t)b * RANKP;
    float4 v = bx[tj * 64 + t];
    jb[t] = v;
    ja[t] = (v.z - v.x) * (v.w - v.y);
    int i = ti * 64 + t;
    float4 bi = bx[i];
    float ai = (bi.z - bi.x) * (bi.w - bi.y);
    __syncthreads();
    u64 word = 0;
    for (int jj = 0; jj < 64; ++jj) {
        int j = tj * 64 + jj;
        float4 bj = jb[jj];
        float xx1 = fmaxf(bi.x, bj.x), yy1 = fmaxf(bi.y, bj.y);
        float xx2 = fminf(bi.z, bj.z), yy2 = fminf(bi.w, bj.w);
        float iw = fmaxf(xx2 - xx1, 0.f), ih = fmaxf(yy2 - yy1, 0.f);
        float inter = iw * ih;
        float iou = inter / (ai + ja[jj] - inter);
        if (j > i && iou > NMS_T) word |= 1ull << jj;
    }
    sup[((size_t)b * RANKP + i) * NWORD + tj] = word;
}

// ---------------- Stage 6b+7: chunked greedy NMS + stable-partition output ----------------
// Per 64-row chunk c: phaseA = readlane diagonal tile from cur (lane w==c holds it);
// phaseB = pure-SALU serial recurrence; step2 = parallel OR of kept rows into remv.
// cur/nxt double-buffer: next chunk's 32 row-words issued BEFORE phaseA so a full
// chunk of compute hides the load latency. __launch_bounds__(64,1): 1-wave kernel,
// let the allocator use ~160 VGPRs so cur+nxt stay resident.
// sup lower-triangle words (w < row's chunk) are NEVER written (0xAA poison from the
// harness) — the `lane >= c` guard keeps them out of remv. Do not remove it.
__global__ __launch_bounds__(64, 1) void k_nms(const u64* __restrict__ valid,
                                               const u64* __restrict__ sup,
                                               const float4* __restrict__ boxes,
                                               float4* __restrict__ out) {
    int b = blockIdx.x;
    int lane = threadIdx.x;           // 64
    int w = lane & 31, hh = lane >> 5;
    const u64* S = sup + (size_t)b * RANKP * NWORD;
    u64 remv = (lane < 32) ? ~valid[(size_t)b * NWORD + lane] : 0ull;
    u64 cur[32], nxt[32];
#pragma unroll
    for (int r = 0; r < 32; ++r)
        cur[r] = S[(size_t)(hh * 32 + r) * NWORD + w];
    int kept_cnt = 0;
    for (int c = 0; c < NWORD; ++c) {
        // prefetch next chunk's rows (wraps at c=31; unused then)
        int cn = (c + 1) & (NWORD - 1);
#pragma unroll
        for (int r = 0; r < 32; ++r)
            nxt[r] = S[(size_t)(cn * 64 + hh * 32 + r) * NWORD + w];
        // ---- phase A+B: diagonal recurrence, batched readlane + pure-SALU chain ----
        u64 scur = readlane_u64(remv, c);
#pragma unroll
        for (int g = 0; g < 4; ++g) {
            u64 d[16];
#pragma unroll
            for (int i = 0; i < 16; ++i)
                d[i] = readlane_u64(cur[(g & 1) * 16 + i], c + (g >> 1) * 32);
#pragma unroll
            for (int i = 0; i < 16; ++i) {
                int row = g * 16 + i;
                if (!((scur >> row) & 1ull)) scur |= d[i];   // s_lshr/s_and/s_cselect/s_or
            }
        }
        u64 kept = ~scur;
        // ---- step2: OR kept rows into remv (parallel, branchless) ----
        uint32_t kk = hh ? (uint32_t)(kept >> 32) : (uint32_t)kept;
        u64 acc = 0;
#pragma unroll
        for (int r = 0; r < 32; ++r) {
            u64 m = (u64)(int64_t)((int32_t)(kk << (31 - r)) >> 31);  // replicate bit r
            acc |= cur[r] & m;
        }
        u64 acco = __shfl(acc, lane + 32);   // partner half's accumulation
        if (lane < 32 && lane >= c) remv |= (acc | acco);
        kept_cnt += (int)__popcll(kept);
#pragma unroll
        for (int r = 0; r < 32; ++r) cur[r] = nxt[r];
        if (kept_cnt >= POST) break;
    }
    // ---- epilogue: stable partition (kept first) -> top-1000 gather ----
    int tot = 0;
    for (int ww = 0; ww < NWORD; ++ww)
        tot += (int)__popcll(~readlane_u64(remv, ww));
    u64 below = (1ull << lane) - 1ull;
    int kcum = 0, ucum = 0;
    for (int ww = 0; ww < NWORD; ++ww) {
        u64 kw = ~readlane_u64(remv, ww);
        int pc = (int)__popcll(kw);
        bool kp = (kw >> lane) & 1ull;
        int pos;
        if (kp) pos = kcum + (int)__popcll(kw & below);
        else    pos = tot + ucum + (int)__popcll((~kw) & below);
        if (pos < POST) out[(size_t)b * POST + pos] = boxes[(size_t)b * RANKP + ww * 64 + lane];
        kcum += pc;
        ucum += 64 - pc;
    }
}

extern "C" void kernel_launch(void* const* d_in, const int* in_sizes, int n_in,
                              void* d_out, int out_size, void* d_ws, size_t ws_size,
                              hipStream_t stream) {
    const float* anchors = (const float*)d_in[0];   // [N,4]
    const float* obj     = (const float*)d_in[1];   // [B,N]
    const float* deltas  = (const float*)d_in[2];   // [B,N,4]
    char* ws = (char*)d_ws;

    uint32_t* hist   = (uint32_t*)(ws + 0);        // 131072
    uint32_t* cnt    = (uint32_t*)(ws + 131072);   // 256
    uint32_t* cut    = (uint32_t*)(ws + 131328);   // 256
    u64*      cand   = (u64*)(ws + 131584);        // B*4096*8 = 262144 -> 393728
    uint32_t* topidx = (uint32_t*)(ws + 393728);   // B*2048*4 = 65536  -> 459264
    float4*   boxes  = (float4*)(ws + 459264);     // B*2048*16 = 524288 -> 983552
    u64*      valid  = (u64*)(ws + 983552);        // 2048 -> 985600
    u64*      sup    = (u64*)(ws + 985600);        // B*2048*32*8 = 4194304 -> 5179904

    hipMemsetAsync(ws, 0, 131328, stream);  // hist + cnt

    dim3 gscan(SCAN_BLOCKS, B);
    k_hist<<<gscan, 256, 0, stream>>>((const float4*)obj, hist);
    k_cut<<<B, 64, 0, stream>>>(hist, cut);
    k_compact<<<gscan, 256, 0, stream>>>((const float4*)obj, cut, cnt, cand);
    k_sort<<<B, 1024, 0, stream>>>(cnt, cand, topidx);
    dim3 gdec(RANKP / 256, B);
    k_decode<<<gdec, 256, 0, stream>>>((const float4*)anchors, (const float4*)deltas,
                                       topidx, boxes, valid);
    dim3 gmask(NTRI, B);
    k_mask<<<gmask, 64, 0, stream>>>(boxes, sup);
    k_nms<<<B, 64, 0, stream>>>(valid, sup, boxes, (float4*)d_out);
}

// Round 7
// 133.608 us; speedup vs baseline: 4.3992x; 1.1493x over previous
//
#include <hip/hip_runtime.h>
#include <stdint.h>

#define B 8
#define N 460800
#define NV4 115200          // N/4 float4 scores per image
#define PRE 2000
#define POST 1000
#define CAP 4096
#define NBIN 4096
#define RANKP 2048
#define NWORD 32
#define NMS_T 0.7f
#define XCLIP 4.135166556742356

#define SCAN_BLOCKS 45      // 45*256*10 = 115200
#define SCAN_ITER 10
#define SCAN_STRIDE (SCAN_BLOCKS * 256)

typedef unsigned long long u64;

__device__ __forceinline__ uint32_t fkey(float f) {
    uint32_t u = __float_as_uint(f);
    return (u & 0x80000000u) ? ~u : (u | 0x80000000u);
}

__device__ __forceinline__ u64 readlane_u64(u64 v, int lane) {
    uint32_t lo = __builtin_amdgcn_readlane((uint32_t)v, lane);
    uint32_t hi = __builtin_amdgcn_readlane((uint32_t)(v >> 32), lane);
    return ((u64)hi << 32) | lo;
}

// ---------------- Stage 1: per-image histogram of score keys (top 12 bits) ----------------
__global__ __launch_bounds__(256) void k_hist(const float4* __restrict__ obj4,
                                              uint32_t* __restrict__ hist) {
    __shared__ uint32_t lh[2][NBIN];   // 32 KiB, 2-way replicated to cut contention
    int b = blockIdx.y;
    for (int i = threadIdx.x; i < NBIN; i += 256) { lh[0][i] = 0; lh[1][i] = 0; }
    __syncthreads();
    const float4* s = obj4 + (size_t)b * NV4;
    int t0 = blockIdx.x * 256 + threadIdx.x;
    uint32_t* h = lh[threadIdx.x & 1];
    float4 v[SCAN_ITER];
#pragma unroll
    for (int k = 0; k < SCAN_ITER; ++k) v[k] = s[t0 + k * SCAN_STRIDE];
#pragma unroll
    for (int k = 0; k < SCAN_ITER; ++k) {
        atomicAdd(&h[fkey(v[k].x) >> 20], 1u);
        atomicAdd(&h[fkey(v[k].y) >> 20], 1u);
        atomicAdd(&h[fkey(v[k].z) >> 20], 1u);
        atomicAdd(&h[fkey(v[k].w) >> 20], 1u);
    }
    __syncthreads();
    uint32_t* gh = hist + (size_t)b * NBIN;
    for (int i = threadIdx.x; i < NBIN; i += 256) {
        uint32_t s2 = lh[0][i] + lh[1][i];
        if (s2) atomicAdd(&gh[i], s2);
    }
}

// ---------------- Stage 2: find cutoff bin (2000th largest falls in it) ----------------
__global__ void k_cut(const uint32_t* __restrict__ hist, uint32_t* __restrict__ cut) {
    int b = blockIdx.x;
    int lane = threadIdx.x;  // 0..63, one wave
    const uint32_t* h = hist + (size_t)b * NBIN;
    uint32_t gs = 0;
    for (int t = 0; t < 64; ++t) gs += h[lane * 64 + t];
    uint32_t suf = gs;
    for (int d = 1; d < 64; d <<= 1) {
        uint32_t v = __shfl_down(suf, d);
        if (lane + d < 64) suf += v;
    }
    unsigned long long m = __ballot(suf >= PRE);
    int G = 63 - __clzll(m);
    uint32_t A = 0;
    if (G < 63) A = __shfl(suf, G + 1);
    uint32_t hv = h[G * 64 + lane];
    uint32_t suf2 = hv;
    for (int d = 1; d < 64; d <<= 1) {
        uint32_t v = __shfl_down(suf2, d);
        if (lane + d < 64) suf2 += v;
    }
    unsigned long long m2 = __ballot(A + suf2 >= PRE);
    int t2 = 63 - __clzll(m2);
    if (lane == 0) cut[b] = (uint32_t)(G * 64 + t2);
}

// ---------------- Stage 3: compact candidates (bin >= cut), 1 global atomic / block ------
#define LBUF 2048
__global__ __launch_bounds__(256) void k_compact(const float4* __restrict__ obj4,
                                                 const uint32_t* __restrict__ cut,
                                                 uint32_t* __restrict__ cnt,
                                                 u64* __restrict__ cand) {
    __shared__ u64 buf[LBUF];          // 16 KiB
    __shared__ uint32_t lcnt, base;
    int b = blockIdx.y;
    if (threadIdx.x == 0) lcnt = 0;
    __syncthreads();
    uint32_t cb = cut[b];
    const float4* s = obj4 + (size_t)b * NV4;
    int t0 = blockIdx.x * 256 + threadIdx.x;
    float4 v[SCAN_ITER];
#pragma unroll
    for (int k = 0; k < SCAN_ITER; ++k) v[k] = s[t0 + k * SCAN_STRIDE];
#pragma unroll
    for (int k = 0; k < SCAN_ITER; ++k) {
        int i4 = (t0 + k * SCAN_STRIDE) * 4;
        float fv[4] = {v[k].x, v[k].y, v[k].z, v[k].w};
#pragma unroll
        for (int c = 0; c < 4; ++c) {
            uint32_t key = fkey(fv[c]);
            if ((key >> 20) >= cb) {
                uint32_t p = atomicAdd(&lcnt, 1u);
                u64 e = ((u64)key << 32) | (uint32_t)(~(uint32_t)(i4 + c));
                if (p < LBUF) buf[p] = e;
                else {   // never expected; correctness fallback
                    uint32_t g = atomicAdd(&cnt[b], 1u);
                    if (g < CAP) cand[(size_t)b * CAP + g] = e;
                }
            }
        }
    }
    __syncthreads();
    uint32_t nb = lcnt < LBUF ? lcnt : LBUF;
    if (threadIdx.x == 0) base = atomicAdd(&cnt[b], nb);
    __syncthreads();
    uint32_t bs = base;
    for (uint32_t t = threadIdx.x; t < nb; t += 256) {
        uint32_t g = bs + t;
        if (g < CAP) cand[(size_t)b * CAP + g] = buf[t];
    }
}

// ---------------- Stage 4: hybrid register/shfl/LDS bitonic sort, desc by (key, ~idx) ----
// 1024 threads x 4 elements in registers (e = tid*4+i).
// j=1,2: in-thread; j=4..128: __shfl_xor (lane delta j/4 <= 32, no barrier);
// j>=256: LDS exchange (2 barriers). 20 barriers total vs 78 for LDS-only.
__device__ __forceinline__ u64 bmax(u64 a, u64 b) { return a > b ? a : b; }
__device__ __forceinline__ u64 bmin(u64 a, u64 b) { return a < b ? a : b; }

__global__ __launch_bounds__(1024) void k_sort(const uint32_t* __restrict__ cnt,
                                               const u64* __restrict__ cand,
                                               uint32_t* __restrict__ topidx) {
    __shared__ u64 sm[CAP];  // 32 KiB
    int b = blockIdx.x;
    uint32_t n = cnt[b]; if (n > CAP) n = CAP;
    const u64* c = cand + (size_t)b * CAP;
    int tid = threadIdx.x;
    int e0 = tid * 4;
    u64 v[4];
#pragma unroll
    for (int i = 0; i < 4; ++i) v[i] = (e0 + i < (int)n) ? c[e0 + i] : 0ull;

    for (unsigned k = 2; k <= CAP; k <<= 1) {
        for (unsigned j = k >> 1; j; j >>= 1) {
            if (j >= 256) {
                // LDS exchange phase
                __syncthreads();   // protect sm from previous phase's readers
#pragma unroll
                for (int i = 0; i < 4; ++i) sm[e0 + i] = v[i];
                __syncthreads();
#pragma unroll
                for (int i = 0; i < 4; ++i) {
                    int e = e0 + i;
                    u64 o = sm[e ^ j];
                    bool lower = (e & j) == 0;
                    bool desc  = (e & k) == 0;
                    v[i] = (lower == desc) ? bmax(v[i], o) : bmin(v[i], o);
                }
            } else if (j >= 4) {
                int ld = j >> 2;   // lane xor, 1..32
#pragma unroll
                for (int i = 0; i < 4; ++i) {
                    int e = e0 + i;
                    u64 o = __shfl_xor(v[i], ld);
                    bool lower = (e & j) == 0;
                    bool desc  = (e & k) == 0;
                    v[i] = (lower == desc) ? bmax(v[i], o) : bmin(v[i], o);
                }
            } else {
                // in-thread phase, j in {1,2}
#pragma unroll
                for (int i = 0; i < 4; ++i) {
                    int e = e0 + i;
                    if ((e & j) == 0) {
                        int i2 = i + (int)j;
                        bool desc = (e & k) == 0;
                        u64 mx = bmax(v[i], v[i2]), mn = bmin(v[i], v[i2]);
                        v[i]  = desc ? mx : mn;
                        v[i2] = desc ? mn : mx;
                    }
                }
            }
        }
    }
#pragma unroll
    for (int i = 0; i < 4; ++i) {
        int r = e0 + i;
        if (r < PRE) topidx[(size_t)b * RANKP + r] = ~(uint32_t)v[i];
    }
}

// ---------------- Stage 5: decode + clip + small-box mask for top-2000 ----------------
__global__ void k_decode(const float4* __restrict__ anchors, const float4* __restrict__ deltas,
                         const uint32_t* __restrict__ topidx, float4* __restrict__ boxes,
                         u64* __restrict__ valid) {
    int b = blockIdx.y;
    int r = blockIdx.x * blockDim.x + threadIdx.x;  // 0..2047
    float4 out = make_float4(0.f, 0.f, 0.f, 0.f);
    bool ok = false;
    if (r < PRE) {
        uint32_t i = topidx[(size_t)b * RANKP + r];
        if (i < N) {
            float4 a = anchors[i];
            float4 d = deltas[(size_t)b * N + i];
            float w = a.z - a.x, h = a.w - a.y;
            float cx = a.x + 0.5f * w, cy = a.y + 0.5f * h;
            float dw = fminf(d.z, (float)XCLIP);
            float dh = fminf(d.w, (float)XCLIP);
            float pcx = d.x * w + cx, pcy = d.y * h + cy;
            float pw = expf(dw) * w, ph = expf(dh) * h;
            float x1 = pcx - 0.5f * pw, y1 = pcy - 0.5f * ph;
            float x2 = pcx + 0.5f * pw, y2 = pcy + 0.5f * ph;
            x1 = fminf(fmaxf(x1, 0.f), 1024.f);
            y1 = fminf(fmaxf(y1, 0.f), 1024.f);
            x2 = fminf(fmaxf(x2, 0.f), 1024.f);
            y2 = fminf(fmaxf(y2, 0.f), 1024.f);
            out = make_float4(x1, y1, x2, y2);
            ok = !((x2 - x1 < 1e-3f) || (y2 - y1 < 1e-3f));
        }
    }
    boxes[(size_t)b * RANKP + r] = out;
    u64 bal = __ballot(ok);
    if ((threadIdx.x & 63) == 0) valid[(size_t)b * NWORD + (r >> 6)] = bal;
}

// ---------------- Stage 6a: pairwise suppression bitmask (triangular grid) ----------------
#define NTRI (NWORD * (NWORD + 1) / 2)   // 528
__global__ void k_mask(const float4* __restrict__ boxes, u64* __restrict__ sup) {
    int b = blockIdx.y;
    int L = blockIdx.x;
    int ti = 0, rem = L;
    while (rem >= NWORD - ti) { rem -= NWORD - ti; ++ti; }
    int tj = ti + rem;
    __shared__ float4 jb[64];
    __shared__ float ja[64];
    int t = threadIdx.x;  // 64 threads
    const float4* bx = boxes + (size_t)b * RANKP;
    float4 v = bx[tj * 64 + t];
    jb[t] = v;
    ja[t] = (v.z - v.x) * (v.w - v.y);
    int i = ti * 64 + t;
    float4 bi = bx[i];
    float ai = (bi.z - bi.x) * (bi.w - bi.y);
    __syncthreads();
    u64 word = 0;
    for (int jj = 0; jj < 64; ++jj) {
        int j = tj * 64 + jj;
        float4 bj = jb[jj];
        float xx1 = fmaxf(bi.x, bj.x), yy1 = fmaxf(bi.y, bj.y);
        float xx2 = fminf(bi.z, bj.z), yy2 = fminf(bi.w, bj.w);
        float iw = fmaxf(xx2 - xx1, 0.f), ih = fmaxf(yy2 - yy1, 0.f);
        float inter = iw * ih;
        float iou = inter / (ai + ja[jj] - inter);
        if (j > i && iou > NMS_T) word |= 1ull << jj;
    }
    sup[((size_t)b * RANKP + i) * NWORD + tj] = word;
}

// ---------------- Stage 6b+7: chunked greedy NMS + stable-partition output ----------------
// Per 64-row chunk c: phaseA = readlane diagonal tile from cur (lane w==c holds it);
// phaseB = pure-SALU serial recurrence; step2 = parallel OR of kept rows into remv.
// cur/nxt double-buffer: next chunk's 32 row-words issued BEFORE phaseA so a full
// chunk of compute hides the load latency. __launch_bounds__(64,1): 1-wave kernel,
// let the allocator use ~160 VGPRs so cur+nxt stay resident.
// sup lower-triangle words (w < row's chunk) are NEVER written (0xAA poison from the
// harness) — the `lane >= c` guard keeps them out of remv. Do not remove it.
__global__ __launch_bounds__(64, 1) void k_nms(const u64* __restrict__ valid,
                                               const u64* __restrict__ sup,
                                               const float4* __restrict__ boxes,
                                               float4* __restrict__ out) {
    int b = blockIdx.x;
    int lane = threadIdx.x;           // 64
    int w = lane & 31, hh = lane >> 5;
    const u64* S = sup + (size_t)b * RANKP * NWORD;
    u64 remv = (lane < 32) ? ~valid[(size_t)b * NWORD + lane] : 0ull;
    u64 cur[32], nxt[32];
#pragma unroll
    for (int r = 0; r < 32; ++r)
        cur[r] = S[(size_t)(hh * 32 + r) * NWORD + w];
    int kept_cnt = 0;
    for (int c = 0; c < NWORD; ++c) {
        // prefetch next chunk's rows (wraps at c=31; unused then)
        int cn = (c + 1) & (NWORD - 1);
#pragma unroll
        for (int r = 0; r < 32; ++r)
            nxt[r] = S[(size_t)(cn * 64 + hh * 32 + r) * NWORD + w];
        // ---- phase A+B: diagonal recurrence, batched readlane + pure-SALU chain ----
        u64 scur = readlane_u64(remv, c);
#pragma unroll
        for (int g = 0; g < 4; ++g) {
            u64 d[16];
#pragma unroll
            for (int i = 0; i < 16; ++i)
                d[i] = readlane_u64(cur[(g & 1) * 16 + i], c + (g >> 1) * 32);
#pragma unroll
            for (int i = 0; i < 16; ++i) {
                int row = g * 16 + i;
                if (!((scur >> row) & 1ull)) scur |= d[i];   // s_lshr/s_and/s_cselect/s_or
            }
        }
        u64 kept = ~scur;
        // ---- step2: OR kept rows into remv (parallel, branchless) ----
        uint32_t kk = hh ? (uint32_t)(kept >> 32) : (uint32_t)kept;
        u64 acc = 0;
#pragma unroll
        for (int r = 0; r < 32; ++r) {
            u64 m = (u64)(int64_t)((int32_t)(kk << (31 - r)) >> 31);  // replicate bit r
            acc |= cur[r] & m;
        }
        u64 acco = __shfl(acc, lane + 32);   // partner half's accumulation
        if (lane < 32 && lane >= c) remv |= (acc | acco);
        kept_cnt += (int)__popcll(kept);
#pragma unroll
        for (int r = 0; r < 32; ++r) cur[r] = nxt[r];
        if (kept_cnt >= POST) break;
    }
    // ---- epilogue: stable partition (kept first) -> top-1000 gather ----
    int tot = 0;
    for (int ww = 0; ww < NWORD; ++ww)
        tot += (int)__popcll(~readlane_u64(remv, ww));
    u64 below = (1ull << lane) - 1ull;
    int kcum = 0, ucum = 0;
    for (int ww = 0; ww < NWORD; ++ww) {
        u64 kw = ~readlane_u64(remv, ww);
        int pc = (int)__popcll(kw);
        bool kp = (kw >> lane) & 1ull;
        int pos;
        if (kp) pos = kcum + (int)__popcll(kw & below);
        else    pos = tot + ucum + (int)__popcll((~kw) & below);
        if (pos < POST) out[(size_t)b * POST + pos] = boxes[(size_t)b * RANKP + ww * 64 + lane];
        kcum += pc;
        ucum += 64 - pc;
    }
}

extern "C" void kernel_launch(void* const* d_in, const int* in_sizes, int n_in,
                              void* d_out, int out_size, void* d_ws, size_t ws_size,
                              hipStream_t stream) {
    const float* anchors = (const float*)d_in[0];   // [N,4]
    const float* obj     = (const float*)d_in[1];   // [B,N]
    const float* deltas  = (const float*)d_in[2];   // [B,N,4]
    char* ws = (char*)d_ws;

    uint32_t* hist   = (uint32_t*)(ws + 0);        // 131072
    uint32_t* cnt    = (uint32_t*)(ws + 131072);   // 256
    uint32_t* cut    = (uint32_t*)(ws + 131328);   // 256
    u64*      cand   = (u64*)(ws + 131584);        // B*4096*8 = 262144 -> 393728
    uint32_t* topidx = (uint32_t*)(ws + 393728);   // B*2048*4 = 65536  -> 459264
    float4*   boxes  = (float4*)(ws + 459264);     // B*2048*16 = 524288 -> 983552
    u64*      valid  = (u64*)(ws + 983552);        // 2048 -> 985600
    u64*      sup    = (u64*)(ws + 985600);        // B*2048*32*8 = 4194304 -> 5179904

    hipMemsetAsync(ws, 0, 131328, stream);  // hist + cnt

    dim3 gscan(SCAN_BLOCKS, B);
    k_hist<<<gscan, 256, 0, stream>>>((const float4*)obj, hist);
    k_cut<<<B, 64, 0, stream>>>(hist, cut);
    k_compact<<<gscan, 256, 0, stream>>>((const float4*)obj, cut, cnt, cand);
    k_sort<<<B, 1024, 0, stream>>>(cnt, cand, topidx);
    dim3 gdec(RANKP / 256, B);
    k_decode<<<gdec, 256, 0, stream>>>((const float4*)anchors, (const float4*)deltas,
                                       topidx, boxes, valid);
    dim3 gmask(NTRI, B);
    k_mask<<<gmask, 64, 0, stream>>>(boxes, sup);
    k_nms<<<B, 64, 0, stream>>>(valid, sup, boxes, (float4*)d_out);
}